// Round 8
// baseline (558.436 us; speedup 1.0000x reference)
//
#include <hip/hip_runtime.h>
#include <math.h>

#define PI_F 3.14159265358979323846f

// ---------------------------------------------------------------------------
// GF(2) deferred-CNOT bookkeeping + 4-gate fusion tables, ALL at compile time.
// CNOTs are index relabelings tracked in M / M^-1; Rot on logical wire w pairs
// p <-> p^col[w], role = parity(p & row[w]); within a layer
// parity(col[j] & row[i]) = delta_ij so 4 gates tile the state into 256
// cosets of 16 amps. Layer 0 Rots fold into the product-state init.
// Grouping is retried from 12 rotated seeds to find fully "strict" groups
// (span free of low-4-only combos -> all pivots >= bit 4 -> conflict-free
// b64 LDS across each wave).
// ---------------------------------------------------------------------------
struct Tab {
    unsigned gmask[15][4];   // pairing masks per pass
    unsigned grole[15][4];   // role parity rows per pass
    int      ggate[15][4];   // gate index into ctab (layer*12 + wire)
    unsigned ghb[15][4];     // pivot bits (1u<<h), sorted ascending
    unsigned zrow[12];       // final measurement parity rows
};

constexpr Tab make_tab() {
    Tab tb{};
    unsigned col[12] = {}, row[12] = {};
    for (int w = 0; w < 12; ++w) { col[w] = 1u << (11 - w); row[w] = 1u << (11 - w); }
    // layer 0: Rots folded into init; apply its CNOTs (r = 1)
    for (int w = 0; w < 12; ++w) {
        const int c = w, tg = (w + 1) % 12;
        col[c] ^= col[tg];
        row[tg] ^= row[c];
    }
    int pass = 0;
    for (int l = 1; l < 6; ++l) {
        unsigned gm[3][4] = {}, gr[3][4] = {};
        int gg[3][4] = {};
        bool found = false;
        // multi-seed strict-only search
        for (int seed = 0; seed < 12 && !found; ++seed) {
            bool used[12] = {};
            bool ok_all = true;
            unsigned tgm[3][4] = {}, tgr[3][4] = {};
            int tgg[3][4] = {};
            for (int grp = 0; grp < 3 && ok_all; ++grp) {
                int ns = 0;
                unsigned spanv[16] = {};
                int nspan = 1;
                for (int ww = 0; ww < 12 && ns < 4; ++ww) {
                    const int w = (ww + seed) % 12;
                    if (used[w]) continue;
                    bool ok = true;
                    for (int s2 = 0; s2 < nspan; ++s2) {
                        const unsigned comb = spanv[s2] ^ col[w];
                        if (comb != 0u && (comb & ~0xFu) == 0u) { ok = false; break; }
                    }
                    if (!ok) continue;
                    for (int s2 = 0; s2 < nspan; ++s2) spanv[nspan + s2] = spanv[s2] ^ col[w];
                    nspan *= 2;
                    used[w] = true;
                    tgm[grp][ns] = col[w]; tgr[grp][ns] = row[w]; tgg[grp][ns] = l * 12 + w;
                    ++ns;
                }
                if (ns < 4) ok_all = false;
            }
            if (ok_all) {
                for (int g2 = 0; g2 < 3; ++g2)
                    for (int i = 0; i < 4; ++i) {
                        gm[g2][i] = tgm[g2][i]; gr[g2][i] = tgr[g2][i]; gg[g2][i] = tgg[g2][i];
                    }
                found = true;
            }
        }
        if (!found) {
            // fallback: strict-then-relaxed greedy (R7 behavior)
            bool used[12] = {};
            for (int grp = 0; grp < 3; ++grp) {
                int ns = 0;
                unsigned spanv[16] = {};
                int nspan = 1;
                for (int w = 0; w < 12 && ns < 4; ++w) {
                    if (used[w]) continue;
                    bool ok = true;
                    for (int s2 = 0; s2 < nspan; ++s2) {
                        const unsigned comb = spanv[s2] ^ col[w];
                        if (comb != 0u && (comb & ~0xFu) == 0u) { ok = false; break; }
                    }
                    if (!ok) continue;
                    for (int s2 = 0; s2 < nspan; ++s2) spanv[nspan + s2] = spanv[s2] ^ col[w];
                    nspan *= 2;
                    used[w] = true;
                    gm[grp][ns] = col[w]; gr[grp][ns] = row[w]; gg[grp][ns] = l * 12 + w;
                    ++ns;
                }
                for (int w = 0; w < 12 && ns < 4; ++w) {
                    if (used[w]) continue;
                    for (int s2 = 0; s2 < nspan; ++s2) spanv[nspan + s2] = spanv[s2] ^ col[w];
                    nspan *= 2;
                    used[w] = true;
                    gm[grp][ns] = col[w]; gr[grp][ns] = row[w]; gg[grp][ns] = l * 12 + w;
                    ++ns;
                }
            }
        }
        // pivots per group (prefer bits >= 4) + emit passes
        for (int grp = 0; grp < 3; ++grp) {
            for (int i = 0; i < 4; ++i) {
                tb.gmask[pass][i] = gm[grp][i];
                tb.grole[pass][i] = gr[grp][i];
                tb.ggate[pass][i] = gg[grp][i];
            }
            unsigned em[4] = {};
            int hp[4] = {};
            for (int i = 0; i < 4; ++i) {
                unsigned e = gm[grp][i];
                for (int j = 0; j < i; ++j)
                    if (e & (1u << hp[j])) e ^= em[j];
                int h = -1;
                for (int bb = 11; bb >= 4; --bb) if (e & (1u << bb)) { h = bb; break; }
                if (h < 0) { for (int bb = 3; bb >= 0; --bb) if (e & (1u << bb)) { h = bb; break; } }
                em[i] = e; hp[i] = h;
            }
            for (int i = 0; i < 4; ++i)
                for (int j = i + 1; j < 4; ++j)
                    if (hp[j] < hp[i]) { int tmp = hp[i]; hp[i] = hp[j]; hp[j] = tmp; }
            for (int i = 0; i < 4; ++i) tb.ghb[pass][i] = 1u << hp[i];
            ++pass;
        }
        const int r = l + 1;
        for (int w = 0; w < 12; ++w) {
            const int c = w, tg = (w + r) % 12;
            col[c] ^= col[tg];
            row[tg] ^= row[c];
        }
    }
    for (int w = 0; w < 12; ++w) tb.zrow[w] = row[w];
    return tb;
}

__constant__ Tab GT = make_tab();

__device__ __forceinline__ float2 cmul(float2 A, float2 B) {
    return make_float2(A.x * B.x - A.y * B.y, A.x * B.y + A.y * B.x);
}

// one 2x2 complex butterfly on two NAMED register operands
__device__ __forceinline__ void bf(float2& X, float2& Y,
                                   float Ar, float Ai, float Br, float Bi,
                                   float Cr, float Ci, float Dr, float Di) {
    const float2 x = X, y = Y;
    X.x = Ar * x.x - Ai * x.y + Br * y.x - Bi * y.y;
    X.y = Ar * x.y + Ai * x.x + Br * y.y + Bi * y.x;
    Y.x = Cr * x.x - Ci * x.y + Dr * y.x - Di * y.y;
    Y.y = Cr * x.y + Ci * x.x + Dr * y.y + Di * y.x;
}

__device__ __forceinline__ unsigned expand4(unsigned j, unsigned h0, unsigned h1,
                                            unsigned h2, unsigned h3) {
    j = (j << 1) - (j & (h0 - 1u));
    j = (j << 1) - (j & (h1 - 1u));
    j = (j << 1) - (j & (h2 - 1u));
    j = (j << 1) - (j & (h3 - 1u));
    return j;
}

// ---------------------------------------------------------------------------
// One block (128 threads, 2 waves) per batch element. State float2 st[4096]
// in LDS. 15 fused passes; each thread owns TWO 16-amp cosets (t and t+128)
// in NAMED registers -> 2x independent work between barriers; barriers span
// only 2 waves. Gray-code rolling addresses + opaque asm (R5/R7 lessons).
// ---------------------------------------------------------------------------
__global__ __launch_bounds__(128) void qvl_fused(
    const float* __restrict__ v,        // (B, 512)
    const float* __restrict__ Wc,       // (12, 512)
    const float* __restrict__ bc,       // (12,)
    const float* __restrict__ weights,  // (6, 12, 3)
    float* __restrict__ out)            // (B, 12)
{
    __shared__ float2 st[4096];     // 32 KB state
    __shared__ float  ctab[72][8];  // Rot coefficients
    __shared__ float2 awv[12], bwv[12];
    __shared__ float  red[12][2];

    const int t    = threadIdx.x;
    const int lane = t & 63;
    const int wv   = t >> 6;
    const int b    = blockIdx.x;

    // ---- Rot coefficient table (batch-independent; per-block) --------------
    if (t < 72) {
        const float phi = weights[t * 3 + 0];
        const float th  = weights[t * 3 + 1];
        const float om  = weights[t * 3 + 2];
        const float hs = 0.5f * (phi + om), hd = 0.5f * (phi - om), ht = 0.5f * th;
        const float ctt = cosf(ht), stt = sinf(ht);
        const float cs = cosf(hs), ss = sinf(hs);
        const float cd = cosf(hd), sd = sinf(hd);
        ctab[t][0] = cs * ctt;  ctab[t][1] = -ss * ctt;   // u00
        ctab[t][2] = -cd * stt; ctab[t][3] = -sd * stt;   // u01
        ctab[t][4] = cd * stt;  ctab[t][5] = -sd * stt;   // u10
        ctab[t][6] = cs * ctt;  ctab[t][7] = ss * ctt;    // u11
    }

    // ---- x_w = tanh(v[b] . Wc[w] + bc[w]) * pi -----------------------------
    {
        const float4 vv = reinterpret_cast<const float4*>(v + b * 512)[t];
        #pragma unroll
        for (int w = 0; w < 12; ++w) {
            const float4 ww = reinterpret_cast<const float4*>(Wc + w * 512)[t];
            float p = vv.x * ww.x + vv.y * ww.y + vv.z * ww.z + vv.w * ww.w;
            #pragma unroll
            for (int s = 1; s < 64; s <<= 1) p += __shfl_xor(p, s, 64);
            if (lane == 0) red[w][wv] = p;
        }
    }
    __syncthreads();
    if (t < 12) {
        // fold RY(x) then layer-0 Rot (gate t) into per-wire 2-vectors
        const float x = tanhf(red[t][0] + red[t][1] + bc[t]) * PI_F;
        const float h = 0.5f * x;
        const float c = cosf(h), s = sinf(h);
        awv[t] = make_float2(ctab[t][0] * c + ctab[t][2] * s,
                             ctab[t][1] * c + ctab[t][3] * s);
        bwv[t] = make_float2(ctab[t][4] * c + ctab[t][6] * s,
                             ctab[t][5] * c + ctab[t][7] * s);
    }
    __syncthreads();

    // ---- init: product state; p = k*128 + t (t = bits 0..6, k = bits 7..11)
    {
        float2 hi = (t & 1) ? bwv[11] : awv[11];   // p bit j -> wire 11-j
        #pragma unroll
        for (int j = 1; j < 7; ++j)
            hi = cmul(hi, ((t >> j) & 1) ? bwv[11 - j] : awv[11 - j]);
        float2 fA[4], fB2[4], fB[8];
        #pragma unroll
        for (int m = 0; m < 4; ++m) {
            fA[m]  = cmul((m & 1) ? bwv[4] : awv[4], (m & 2) ? bwv[3] : awv[3]);
            fB2[m] = cmul((m & 1) ? bwv[2] : awv[2], (m & 2) ? bwv[1] : awv[1]);
        }
        #pragma unroll
        for (int m = 0; m < 8; ++m)
            fB[m] = cmul(fB2[m & 3], (m & 4) ? bwv[0] : awv[0]);
        #pragma unroll
        for (int k = 0; k < 32; ++k)
            st[k * 128 + t] = cmul(hi, cmul(fA[k & 3], fB[k >> 2]));
    }

    // ---- 15 fused passes (layers 1..5, 4 gates each, 2 cosets/thread) ------
    #pragma unroll 1
    for (int ps = 0; ps < 15; ++ps) {
        __syncthreads();
        const unsigned m0 = GT.gmask[ps][0], m1 = GT.gmask[ps][1];
        const unsigned m2 = GT.gmask[ps][2], m3 = GT.gmask[ps][3];
        const unsigned h0 = GT.ghb[ps][0], h1 = GT.ghb[ps][1];
        const unsigned h2 = GT.ghb[ps][2], h3 = GT.ghb[ps][3];
        unsigned q0 = expand4((unsigned)t, h0, h1, h2, h3);
        unsigned q1 = expand4((unsigned)t + 128u, h0, h1, h2, h3);

        // Gray-code load chains (one rolling address each)
        #define LOADC(P, Q)                                  \
            unsigned ad##P = (Q);                            \
            float2 P##0  = st[ad##P]; ad##P ^= m0;           \
            float2 P##1  = st[ad##P]; ad##P ^= m1;           \
            float2 P##3  = st[ad##P]; ad##P ^= m0;           \
            float2 P##2  = st[ad##P]; ad##P ^= m2;           \
            float2 P##6  = st[ad##P]; ad##P ^= m0;           \
            float2 P##7  = st[ad##P]; ad##P ^= m1;           \
            float2 P##5  = st[ad##P]; ad##P ^= m0;           \
            float2 P##4  = st[ad##P]; ad##P ^= m3;           \
            float2 P##12 = st[ad##P]; ad##P ^= m0;           \
            float2 P##13 = st[ad##P]; ad##P ^= m1;           \
            float2 P##15 = st[ad##P]; ad##P ^= m0;           \
            float2 P##14 = st[ad##P]; ad##P ^= m2;           \
            float2 P##10 = st[ad##P]; ad##P ^= m0;           \
            float2 P##11 = st[ad##P]; ad##P ^= m1;           \
            float2 P##9  = st[ad##P]; ad##P ^= m0;           \
            float2 P##8  = st[ad##P];

        #define COEFS(LEV, Q)                                                   \
            const int   gi = GT.ggate[ps][LEV];                                 \
            const int   cc = __popc((Q) & GT.grole[ps][LEV]) & 1;               \
            const float e0 = ctab[gi][0], e1 = ctab[gi][1];                     \
            const float e2 = ctab[gi][2], e3 = ctab[gi][3];                     \
            const float e4 = ctab[gi][4], e5 = ctab[gi][5];                     \
            const float e6 = ctab[gi][6], e7 = ctab[gi][7];                     \
            const float Ar = cc ? e6 : e0, Ai = cc ? e7 : e1;                   \
            const float Br = cc ? e4 : e2, Bi = cc ? e5 : e3;                   \
            const float Cr = cc ? e2 : e4, Ci = cc ? e3 : e5;                   \
            const float Dr = cc ? e0 : e6, Di = cc ? e1 : e7;
        #define BF(X, Y) bf(X, Y, Ar, Ai, Br, Bi, Cr, Ci, Dr, Di)

        #define APPLY4(P, Q)                                                    \
            { COEFS(0, Q)                                                       \
              BF(P##0,P##1); BF(P##2,P##3); BF(P##4,P##5); BF(P##6,P##7);       \
              BF(P##8,P##9); BF(P##10,P##11); BF(P##12,P##13); BF(P##14,P##15);}\
            { COEFS(1, Q)                                                       \
              BF(P##0,P##2); BF(P##1,P##3); BF(P##4,P##6); BF(P##5,P##7);       \
              BF(P##8,P##10); BF(P##9,P##11); BF(P##12,P##14); BF(P##13,P##15);}\
            { COEFS(2, Q)                                                       \
              BF(P##0,P##4); BF(P##1,P##5); BF(P##2,P##6); BF(P##3,P##7);       \
              BF(P##8,P##12); BF(P##9,P##13); BF(P##10,P##14); BF(P##11,P##15);}\
            { COEFS(3, Q)                                                       \
              BF(P##0,P##8); BF(P##1,P##9); BF(P##2,P##10); BF(P##3,P##11);     \
              BF(P##4,P##12); BF(P##5,P##13); BF(P##6,P##14); BF(P##7,P##15); }

        #define STOREC(P, Q)                                 \
            unsigned sd##P = (Q);                            \
            st[sd##P] = P##0;  sd##P ^= m0;                  \
            st[sd##P] = P##1;  sd##P ^= m1;                  \
            st[sd##P] = P##3;  sd##P ^= m0;                  \
            st[sd##P] = P##2;  sd##P ^= m2;                  \
            st[sd##P] = P##6;  sd##P ^= m0;                  \
            st[sd##P] = P##7;  sd##P ^= m1;                  \
            st[sd##P] = P##5;  sd##P ^= m0;                  \
            st[sd##P] = P##4;  sd##P ^= m3;                  \
            st[sd##P] = P##12; sd##P ^= m0;                  \
            st[sd##P] = P##13; sd##P ^= m1;                  \
            st[sd##P] = P##15; sd##P ^= m0;                  \
            st[sd##P] = P##14; sd##P ^= m2;                  \
            st[sd##P] = P##10; sd##P ^= m0;                  \
            st[sd##P] = P##11; sd##P ^= m1;                  \
            st[sd##P] = P##9;  sd##P ^= m0;                  \
            st[sd##P] = P##8;

        LOADC(A, q0)
        LOADC(B, q1)
        APPLY4(A, q0)
        APPLY4(B, q1)
        // opaque barrier: store addresses recomputed, not CSE'd from loads
        asm volatile("" : "+v"(q0), "+v"(q1));
        STOREC(A, q0)
        STOREC(B, q1)

        #undef LOADC
        #undef COEFS
        #undef BF
        #undef APPLY4
        #undef STOREC
    }
    __syncthreads();

    // ---- PauliZ expvals; p = k*128 + t, sign = parity(p & zrow) ------------
    float p2[32];
    #pragma unroll
    for (int k = 0; k < 32; ++k) {
        const float2 aa = st[k * 128 + t];
        p2[k] = aa.x * aa.x + aa.y * aa.y;
    }
    #pragma unroll
    for (int w = 0; w < 12; ++w) {
        const unsigned zr = GT.zrow[w];
        const unsigned Aw = (unsigned)__popc((unsigned)t & zr & 0x7Fu) & 1u;
        const unsigned nm = (zr >> 7) & 0x1Fu;
        unsigned Pm = 0u;
        Pm ^= (nm & 1u)  ? 0xAAAAAAAAu : 0u;
        Pm ^= (nm & 2u)  ? 0xCCCCCCCCu : 0u;
        Pm ^= (nm & 4u)  ? 0xF0F0F0F0u : 0u;
        Pm ^= (nm & 8u)  ? 0xFF00FF00u : 0u;
        Pm ^= (nm & 16u) ? 0xFFFF0000u : 0u;
        Pm ^= Aw ? 0xFFFFFFFFu : 0u;
        float z = 0.0f;
        #pragma unroll
        for (int k = 0; k < 32; ++k)
            z += ((Pm >> k) & 1u) ? -p2[k] : p2[k];
        #pragma unroll
        for (int s = 1; s < 64; s <<= 1) z += __shfl_xor(z, s, 64);
        if (lane == 0) red[w][wv] = z;
    }
    __syncthreads();
    if (t < 12)
        out[b * 12 + t] = red[t][0] + red[t][1];
}

extern "C" void kernel_launch(void* const* d_in, const int* in_sizes, int n_in,
                              void* d_out, int out_size, void* d_ws, size_t ws_size,
                              hipStream_t stream) {
    (void)n_in; (void)out_size; (void)d_ws; (void)ws_size;
    const float* v   = (const float*)d_in[0];
    const float* Wc  = (const float*)d_in[1];
    const float* bc  = (const float*)d_in[2];
    const float* wts = (const float*)d_in[3];
    float* out = (float*)d_out;

    const int B = in_sizes[0] / 512;
    qvl_fused<<<B, 128, 0, stream>>>(v, Wc, bc, wts, out);
}

// Round 9
// 360.544 us; speedup vs baseline: 1.5489x; 1.5489x over previous
//
#include <hip/hip_runtime.h>
#include <math.h>

#define PI_F 3.14159265358979323846f

// ---------------------------------------------------------------------------
// GF(2) deferred-CNOT bookkeeping + 4-gate fusion, ALL at compile time.
// CNOTs are index relabelings tracked in M / M^-1; Rot on logical wire w pairs
// p <-> p^col[w], role = parity(p & row[w]); within a layer
// parity(col[j] & row[i]) = delta_ij, so 4 gates tile the state into 256
// cosets of 16 amps. Layer 0 Rots fold into the product-state init.
//
// NEW (R9): per pass, the coset representative is chosen in the NULL SPACE of
// the 4 role rows -> parity(q & r_i) == 0 for ALL levels -> coefficients used
// raw (no per-thread cndmask/popc). The 8-vector null basis is computed here
// and (best-effort) aligned so nb[0..3] have low4 = e_j and nb[4..7] low4 = 0,
// keeping q's low 4 bits = t's low 4 bits (R7's bank behavior).
// ---------------------------------------------------------------------------
struct Tab {
    unsigned gmask[15][4];   // pairing masks per pass
    unsigned grole[15][4];   // role parity rows per pass
    int      ggate[15][4];   // gate index (layer*12 + wire) for coef writer
    unsigned nb[15][8];      // null-space basis; q = XOR_{i: t bit i} nb[i]
    unsigned zrow[12];       // final measurement parity rows
};

constexpr Tab make_tab() {
    Tab tb{};
    unsigned col[12] = {}, row[12] = {};
    for (int w = 0; w < 12; ++w) { col[w] = 1u << (11 - w); row[w] = 1u << (11 - w); }
    // layer 0: Rots folded into init; apply its CNOTs (r = 1)
    for (int w = 0; w < 12; ++w) {
        const int c = w, tg = (w + 1) % 12;
        col[c] ^= col[tg];
        row[tg] ^= row[c];
    }
    int pass = 0;
    for (int l = 1; l < 6; ++l) {
        unsigned gm[3][4] = {}, gr[3][4] = {};
        int gg[3][4] = {};
        bool found = false;
        // multi-seed strict search on ROLE span (banks now depend on roles):
        // reject groups whose role-span contains a nonzero low-4-only combo.
        for (int seed = 0; seed < 12 && !found; ++seed) {
            bool used[12] = {};
            bool ok_all = true;
            unsigned tgm[3][4] = {}, tgr[3][4] = {};
            int tgg[3][4] = {};
            for (int grp = 0; grp < 3 && ok_all; ++grp) {
                int ns = 0;
                unsigned spanv[16] = {};
                int nspan = 1;
                for (int ww = 0; ww < 12 && ns < 4; ++ww) {
                    const int w = (ww + seed) % 12;
                    if (used[w]) continue;
                    bool ok = true;
                    for (int s2 = 0; s2 < nspan; ++s2) {
                        const unsigned comb = spanv[s2] ^ row[w];
                        if (comb != 0u && (comb & ~0xFu) == 0u) { ok = false; break; }
                    }
                    if (!ok) continue;
                    for (int s2 = 0; s2 < nspan; ++s2) spanv[nspan + s2] = spanv[s2] ^ row[w];
                    nspan *= 2;
                    used[w] = true;
                    tgm[grp][ns] = col[w]; tgr[grp][ns] = row[w]; tgg[grp][ns] = l * 12 + w;
                    ++ns;
                }
                if (ns < 4) ok_all = false;
            }
            if (ok_all) {
                for (int g2 = 0; g2 < 3; ++g2)
                    for (int i = 0; i < 4; ++i) {
                        gm[g2][i] = tgm[g2][i]; gr[g2][i] = tgr[g2][i]; gg[g2][i] = tgg[g2][i];
                    }
                found = true;
            }
        }
        if (!found) {
            // fallback greedy (correct regardless; only banks may degrade)
            bool used[12] = {};
            for (int grp = 0; grp < 3; ++grp) {
                int ns = 0;
                for (int w = 0; w < 12 && ns < 4; ++w) {
                    if (used[w]) continue;
                    used[w] = true;
                    gm[grp][ns] = col[w]; gr[grp][ns] = row[w]; gg[grp][ns] = l * 12 + w;
                    ++ns;
                }
            }
        }
        for (int grp = 0; grp < 3; ++grp) {
            for (int i = 0; i < 4; ++i) {
                tb.gmask[pass][i] = gm[grp][i];
                tb.grole[pass][i] = gr[grp][i];
                tb.ggate[pass][i] = gg[grp][i];
            }
            // ---- null-space basis of {p : parity(p & r_i) == 0, i=0..3} ----
            unsigned Rm[4] = { gr[grp][0], gr[grp][1], gr[grp][2], gr[grp][3] };
            int pivc[4] = { -1, -1, -1, -1 };
            int rr = 0;
            const int order[12] = { 11,10,9,8,7,6,5,4,3,2,1,0 };  // prefer high pivots
            for (int ci = 0; ci < 12 && rr < 4; ++ci) {
                const int c = order[ci];
                int sel = -1;
                for (int i = rr; i < 4; ++i) if ((Rm[i] >> c) & 1u) { sel = i; break; }
                if (sel < 0) continue;
                unsigned tmp = Rm[rr]; Rm[rr] = Rm[sel]; Rm[sel] = tmp;
                for (int i = 0; i < 4; ++i)
                    if (i != rr && ((Rm[i] >> c) & 1u)) Rm[i] ^= Rm[rr];
                pivc[rr] = c; ++rr;
            }
            unsigned nbs[8] = {};
            int nn = 0;
            for (int c = 0; c < 12; ++c) {
                bool isp = false;
                for (int i = 0; i < 4; ++i) if (pivc[i] == c) isp = true;
                if (isp) continue;
                unsigned v2 = 1u << c;
                for (int i = 0; i < 4; ++i)
                    if ((Rm[i] >> c) & 1u) v2 |= 1u << pivc[i];
                nbs[nn++] = v2;
            }
            // ---- align low4: RREF the 8 basis rows over columns 0..3 -------
            unsigned vv[8] = {};
            for (int i = 0; i < 8; ++i) vv[i] = nbs[i];
            int pivr[4] = { -1, -1, -1, -1 };
            int rowi = 0;
            for (int c = 0; c < 4 && rowi < 8; ++c) {
                int sel = -1;
                for (int i = rowi; i < 8; ++i) if ((vv[i] >> c) & 1u) { sel = i; break; }
                if (sel < 0) continue;
                unsigned tmp = vv[rowi]; vv[rowi] = vv[sel]; vv[sel] = tmp;
                for (int i = 0; i < 8; ++i)
                    if (i != rowi && ((vv[i] >> c) & 1u)) vv[i] ^= vv[rowi];
                pivr[c] = rowi; ++rowi;
            }
            unsigned fin[8] = {};
            bool rowused[8] = {};
            bool slot[8] = {};
            for (int j = 0; j < 4; ++j)
                if (pivr[j] >= 0) { fin[j] = vv[pivr[j]]; rowused[pivr[j]] = true; slot[j] = true; }
            int fs = 0;
            for (int i = 0; i < 8; ++i) {
                if (rowused[i]) continue;
                while (fs < 8 && slot[fs]) ++fs;
                fin[fs] = vv[i]; slot[fs] = true; ++fs;
            }
            for (int i = 0; i < 8; ++i) tb.nb[pass][i] = fin[i];
            ++pass;
        }
        const int r = l + 1;
        for (int w = 0; w < 12; ++w) {
            const int c = w, tg = (w + r) % 12;
            col[c] ^= col[tg];
            row[tg] ^= row[c];
        }
    }
    for (int w = 0; w < 12; ++w) tb.zrow[w] = row[w];
    return tb;
}

__constant__ Tab GT = make_tab();

// pass-ordered Rot coefs: [pass*32 + lev*8 + j] for 15 passes; layer-0 gates
// (folded into init) at [480 + w*8 + j]. Written every call by rot_coef_kernel.
__device__ float g_coef[576];

__device__ __forceinline__ void rot8(const float* __restrict__ wp, float* o) {
    const float phi = wp[0], th = wp[1], om = wp[2];
    const float hs = 0.5f * (phi + om), hd = 0.5f * (phi - om), ht = 0.5f * th;
    const float ctt = cosf(ht), stt = sinf(ht);
    const float cs = cosf(hs), ss = sinf(hs);
    const float cd = cosf(hd), sd = sinf(hd);
    o[0] = cs * ctt;  o[1] = -ss * ctt;   // u00
    o[2] = -cd * stt; o[3] = -sd * stt;   // u01
    o[4] = cd * stt;  o[5] = -sd * stt;   // u10
    o[6] = cs * ctt;  o[7] = ss * ctt;    // u11
}

__global__ void rot_coef_kernel(const float* __restrict__ weights) {
    const int i = blockIdx.x * blockDim.x + threadIdx.x;
    if (i < 60) {
        const int ps = i >> 2, lev = i & 3;
        const int g = GT.ggate[ps][lev];
        float o[8];
        rot8(weights + g * 3, o);
        #pragma unroll
        for (int j = 0; j < 8; ++j) g_coef[ps * 32 + lev * 8 + j] = o[j];
    } else if (i >= 64 && i < 76) {
        const int w = i - 64;
        float o[8];
        rot8(weights + w * 3, o);
        #pragma unroll
        for (int j = 0; j < 8; ++j) g_coef[480 + w * 8 + j] = o[j];
    }
}

__device__ __forceinline__ float2 cmul(float2 A, float2 B) {
    return make_float2(A.x * B.x - A.y * B.y, A.x * B.y + A.y * B.x);
}

// one 2x2 complex butterfly on two NAMED register operands (coefs are SGPRs)
__device__ __forceinline__ void bf(float2& X, float2& Y,
                                   float Ar, float Ai, float Br, float Bi,
                                   float Cr, float Ci, float Dr, float Di) {
    const float2 x = X, y = Y;
    X.x = Ar * x.x - Ai * x.y + Br * y.x - Bi * y.y;
    X.y = Ar * x.y + Ai * x.x + Br * y.y + Bi * y.x;
    Y.x = Cr * x.x - Ci * x.y + Dr * y.x - Di * y.y;
    Y.y = Cr * x.y + Ci * x.x + Dr * y.y + Di * y.x;
}

// ---------------------------------------------------------------------------
// One block (256 threads) per batch element. LDS = EXACTLY the 32 KB state
// (5 blocks/CU); small scratch (red) overlaid inside st. Coefs from global
// via uniform scalar loads; null-space representatives -> no role selection.
// ---------------------------------------------------------------------------
__global__ __launch_bounds__(256) void qvl_fused(
    const float* __restrict__ v,        // (B, 512)
    const float* __restrict__ Wc,       // (12, 512)
    const float* __restrict__ bc,       // (12,)
    float* __restrict__ out)            // (B, 12)
{
    __shared__ float2 st[4096];     // 32768 B total LDS
    float* redf = reinterpret_cast<float*>(st);   // overlay (48 floats)

    const int t    = threadIdx.x;
    const int lane = t & 63;
    const int wv   = t >> 6;
    const int b    = blockIdx.x;

    // ---- x_w = tanh(v[b] . Wc[w] + bc[w]) * pi (partials into overlay) -----
    {
        const float2 vv = reinterpret_cast<const float2*>(v + b * 512)[t];
        #pragma unroll
        for (int w = 0; w < 12; ++w) {
            const float2 ww = reinterpret_cast<const float2*>(Wc + w * 512)[t];
            float p = vv.x * ww.x + vv.y * ww.y;
            #pragma unroll
            for (int s = 1; s < 64; s <<= 1) p += __shfl_xor(p, s, 64);
            if (lane == 0) redf[w * 4 + wv] = p;
        }
    }
    __syncthreads();

    // ---- per-wave: lanes 0..11 fold RY(x_w) + layer-0 Rot into (aw, bw) ----
    float2 aw = make_float2(0.0f, 0.0f), bw = aw;
    if (lane < 12) {
        const float x = tanhf(redf[lane * 4 + 0] + redf[lane * 4 + 1] +
                              redf[lane * 4 + 2] + redf[lane * 4 + 3] + bc[lane]) * PI_F;
        const float h = 0.5f * x;
        const float c = cosf(h), s = sinf(h);
        const float* c8 = g_coef + 480 + lane * 8;
        aw = make_float2(c8[0] * c + c8[2] * s, c8[1] * c + c8[3] * s);
        bw = make_float2(c8[4] * c + c8[6] * s, c8[5] * c + c8[7] * s);
    }
    __syncthreads();   // overlay reads done before init overwrites st

    // ---- init: product state; p = k*256 + t (t bits -> wires 11..4) --------
    {
        float2 hi = make_float2(1.0f, 0.0f);
        #pragma unroll
        for (int j = 0; j < 8; ++j) {
            const int src = 11 - j;            // wire for p bit j
            const float ax = __shfl(aw.x, src, 64), ay = __shfl(aw.y, src, 64);
            const float bx = __shfl(bw.x, src, 64), by = __shfl(bw.y, src, 64);
            const int bit = (t >> j) & 1;
            hi = cmul(hi, make_float2(bit ? bx : ax, bit ? by : ay));
        }
        float2 A3 = make_float2(__shfl(aw.x, 3, 64), __shfl(aw.y, 3, 64));
        float2 B3 = make_float2(__shfl(bw.x, 3, 64), __shfl(bw.y, 3, 64));
        float2 A2 = make_float2(__shfl(aw.x, 2, 64), __shfl(aw.y, 2, 64));
        float2 B2 = make_float2(__shfl(bw.x, 2, 64), __shfl(bw.y, 2, 64));
        float2 A1 = make_float2(__shfl(aw.x, 1, 64), __shfl(aw.y, 1, 64));
        float2 B1 = make_float2(__shfl(bw.x, 1, 64), __shfl(bw.y, 1, 64));
        float2 A0 = make_float2(__shfl(aw.x, 0, 64), __shfl(aw.y, 0, 64));
        float2 B0 = make_float2(__shfl(bw.x, 0, 64), __shfl(bw.y, 0, 64));
        float2 fA[4], fB[4];
        #pragma unroll
        for (int m = 0; m < 4; ++m) {
            fA[m] = cmul((m & 1) ? B3 : A3, (m & 2) ? B2 : A2);   // p bits 8,9
            fB[m] = cmul((m & 1) ? B1 : A1, (m & 2) ? B0 : A0);   // p bits 10,11
        }
        #pragma unroll
        for (int k = 0; k < 16; ++k)
            st[k * 256 + t] = cmul(hi, cmul(fA[k & 3], fB[k >> 2]));
    }

    // ---- 15 fused passes (layers 1..5, 4 gates each) ------------------------
    #pragma unroll 1
    for (int ps = 0; ps < 15; ++ps) {
        __syncthreads();
        const float* cp = g_coef + ps * 32;    // uniform -> s_load
        const unsigned m0 = GT.gmask[ps][0], m1 = GT.gmask[ps][1];
        const unsigned m2 = GT.gmask[ps][2], m3 = GT.gmask[ps][3];
        // null-space representative for this thread's coset
        unsigned q = 0u;
        #pragma unroll
        for (int i = 0; i < 8; ++i)
            q ^= (t & (1 << i)) ? GT.nb[ps][i] : 0u;

        // Gray-code load chain (one rolling address register)
        unsigned ad = q;
        float2 g0  = st[ad]; ad ^= m0;
        float2 g1  = st[ad]; ad ^= m1;
        float2 g3  = st[ad]; ad ^= m0;
        float2 g2  = st[ad]; ad ^= m2;
        float2 g6  = st[ad]; ad ^= m0;
        float2 g7  = st[ad]; ad ^= m1;
        float2 g5  = st[ad]; ad ^= m0;
        float2 g4  = st[ad]; ad ^= m3;
        float2 g12 = st[ad]; ad ^= m0;
        float2 g13 = st[ad]; ad ^= m1;
        float2 g15 = st[ad]; ad ^= m0;
        float2 g14 = st[ad]; ad ^= m2;
        float2 g10 = st[ad]; ad ^= m0;
        float2 g11 = st[ad]; ad ^= m1;
        float2 g9  = st[ad]; ad ^= m0;
        float2 g8  = st[ad];

        // all representatives have role parity 0 at every level -> raw coefs
        #define BF(X, Y) bf(X, Y, Ar, Ai, Br, Bi, Cr, Ci, Dr, Di)
        { const float Ar = cp[0],  Ai = cp[1],  Br = cp[2],  Bi = cp[3];
          const float Cr = cp[4],  Ci = cp[5],  Dr = cp[6],  Di = cp[7];
          BF(g0,g1); BF(g2,g3); BF(g4,g5); BF(g6,g7);
          BF(g8,g9); BF(g10,g11); BF(g12,g13); BF(g14,g15); }
        { const float Ar = cp[8],  Ai = cp[9],  Br = cp[10], Bi = cp[11];
          const float Cr = cp[12], Ci = cp[13], Dr = cp[14], Di = cp[15];
          BF(g0,g2); BF(g1,g3); BF(g4,g6); BF(g5,g7);
          BF(g8,g10); BF(g9,g11); BF(g12,g14); BF(g13,g15); }
        { const float Ar = cp[16], Ai = cp[17], Br = cp[18], Bi = cp[19];
          const float Cr = cp[20], Ci = cp[21], Dr = cp[22], Di = cp[23];
          BF(g0,g4); BF(g1,g5); BF(g2,g6); BF(g3,g7);
          BF(g8,g12); BF(g9,g13); BF(g10,g14); BF(g11,g15); }
        { const float Ar = cp[24], Ai = cp[25], Br = cp[26], Bi = cp[27];
          const float Cr = cp[28], Ci = cp[29], Dr = cp[30], Di = cp[31];
          BF(g0,g8); BF(g1,g9); BF(g2,g10); BF(g3,g11);
          BF(g4,g12); BF(g5,g13); BF(g6,g14); BF(g7,g15); }
        #undef BF

        // opaque barrier on q: store chain recomputed, not CSE'd with loads
        asm volatile("" : "+v"(q));

        ad = q;
        st[ad] = g0;  ad ^= m0;
        st[ad] = g1;  ad ^= m1;
        st[ad] = g3;  ad ^= m0;
        st[ad] = g2;  ad ^= m2;
        st[ad] = g6;  ad ^= m0;
        st[ad] = g7;  ad ^= m1;
        st[ad] = g5;  ad ^= m0;
        st[ad] = g4;  ad ^= m3;
        st[ad] = g12; ad ^= m0;
        st[ad] = g13; ad ^= m1;
        st[ad] = g15; ad ^= m0;
        st[ad] = g14; ad ^= m2;
        st[ad] = g10; ad ^= m0;
        st[ad] = g11; ad ^= m1;
        st[ad] = g9;  ad ^= m0;
        st[ad] = g8;
    }
    __syncthreads();

    // ---- PauliZ expvals; p = k*256 + t, sign = parity(p & zrow) ------------
    float p2[16];
    #pragma unroll
    for (int k = 0; k < 16; ++k) {
        const float2 aa = st[k * 256 + t];
        p2[k] = aa.x * aa.x + aa.y * aa.y;
    }
    __syncthreads();   // all st reads done before overlay reuse
    #pragma unroll
    for (int w = 0; w < 12; ++w) {
        const unsigned zr = GT.zrow[w];
        const unsigned Aw = (unsigned)__popc((unsigned)t & zr) & 1u;
        const unsigned nm = (zr >> 8) & 0xFu;
        unsigned P = 0u;
        P ^= (nm & 1u) ? 0xAAAAu : 0u;
        P ^= (nm & 2u) ? 0xCCCCu : 0u;
        P ^= (nm & 4u) ? 0xF0F0u : 0u;
        P ^= (nm & 8u) ? 0xFF00u : 0u;
        P ^= Aw ? 0xFFFFu : 0u;
        float z = 0.0f;
        #pragma unroll
        for (int k = 0; k < 16; ++k)
            z += ((P >> k) & 1u) ? -p2[k] : p2[k];
        #pragma unroll
        for (int s = 1; s < 64; s <<= 1) z += __shfl_xor(z, s, 64);
        if (lane == 0) redf[w * 4 + wv] = z;
    }
    __syncthreads();
    if (t < 12)
        out[b * 12 + t] = redf[t * 4 + 0] + redf[t * 4 + 1] +
                          redf[t * 4 + 2] + redf[t * 4 + 3];
}

extern "C" void kernel_launch(void* const* d_in, const int* in_sizes, int n_in,
                              void* d_out, int out_size, void* d_ws, size_t ws_size,
                              hipStream_t stream) {
    (void)n_in; (void)out_size; (void)d_ws; (void)ws_size;
    const float* v   = (const float*)d_in[0];
    const float* Wc  = (const float*)d_in[1];
    const float* bc  = (const float*)d_in[2];
    const float* wts = (const float*)d_in[3];
    float* out = (float*)d_out;

    const int B = in_sizes[0] / 512;
    rot_coef_kernel<<<1, 128, 0, stream>>>(wts);
    qvl_fused<<<B, 256, 0, stream>>>(v, Wc, bc, out);
}